// Round 2
// baseline (146.109 us; speedup 1.0000x reference)
//
#include <hip/hip_runtime.h>
#include <hip/hip_bf16.h>

#define NN 8192
#define BM 32
#define BK 256
#define XD_LEN 16448   // per-channel duplicated x length (covers i0+j0+window)
#define XW_LEN 304     // per-tile x window length

typedef short bfrag8 __attribute__((ext_vector_type(8)));   // 8 bf16 in 4 VGPRs
typedef float floatx4 __attribute__((ext_vector_type(4)));

static __device__ __forceinline__ unsigned short f2bf(float f) {
  unsigned u = __builtin_bit_cast(unsigned, f);
  u = (u + 0x7FFFu + ((u >> 16) & 1u)) >> 16;   // RNE
  return (unsigned short)u;
}
static __device__ __forceinline__ float bf2f(unsigned short h) {
  unsigned u = ((unsigned)h) << 16;
  return __builtin_bit_cast(float, u);
}
static __device__ __forceinline__ float elu(float v) {
  return v > 0.f ? v : expm1f(v);
}

// ---------------- prep: W1^T bf16, W2^T bf16, duplicated bf16 x, regu sums ---
__global__ void prep_kernel(const float* __restrict__ x, const float* __restrict__ W1,
                            const float* __restrict__ W2, const float* __restrict__ rlen,
                            unsigned short* __restrict__ W1T, unsigned short* __restrict__ W2T,
                            unsigned short* __restrict__ xd, float* __restrict__ acc) {
  const int b = blockIdx.x, t = threadIdx.x;
  if (b < 128) {
    // transpose a 64x64 tile of W1 (8192x64) -> W1T (64x8192) bf16
    __shared__ float tile[64][65];
    const int k0 = b * 64;
#pragma unroll
    for (int it = 0; it < 16; ++it) {
      int k = it * 4 + (t >> 6);
      tile[k][t & 63] = W1[(k0 + k) * 64 + (t & 63)];
    }
    __syncthreads();
#pragma unroll
    for (int it = 0; it < 16; ++it) {
      int f = it * 4 + (t >> 6);
      int kk = t & 63;
      W1T[f * NN + k0 + kk] = f2bf(tile[kk][f]);
    }
  } else if (b == 128) {
    for (int idx = t; idx < 64 * 64; idx += 256) {
      int k = idx >> 6, f = idx & 63;
      W2T[f * 64 + k] = f2bf(W2[idx]);
    }
  } else if (b == 129) {
    for (int c = 0; c < 3; ++c)
      for (int e = t * 4; e < XD_LEN; e += 1024) {
        float4 v = *(const float4*)&x[c * NN + (e & (NN - 1))];
        ushort4 o;
        o.x = f2bf(v.x); o.y = f2bf(v.y); o.z = f2bf(v.z); o.w = f2bf(v.w);
        *(ushort4*)&xd[c * XD_LEN + e] = o;
      }
  } else {
    // blocks 130,131: x2 = sum_c x^2; s1 = sum x2, s2 = sum exp(x2/(2 L^2))
    float rl = rlen[0];
    float inv = 1.f / (2.f * rl * rl);
    int base = (b - 130) * 4096;
    float s1 = 0.f, s2 = 0.f;
    for (int ii = 0; ii < 16; ++ii) {
      int i = base + ii * 256 + t;
      float a0 = x[i], a1 = x[NN + i], a2 = x[2 * NN + i];
      float s = a0 * a0 + a1 * a1 + a2 * a2;
      s1 += s; s2 += expf(s * inv);
    }
    for (int d = 32; d > 0; d >>= 1) { s1 += __shfl_down(s1, d); s2 += __shfl_down(s2, d); }
    __shared__ float p1[4], p2[4];
    if ((t & 63) == 0) { p1[t >> 6] = s1; p2[t >> 6] = s2; }
    __syncthreads();
    if (t == 0) {
      atomicAdd(&acc[1], p1[0] + p1[1] + p1[2] + p1[3]);
      atomicAdd(&acc[2], p2[0] + p2[1] + p2[2] + p2[3]);
    }
  }
}

// ---------------- main: fused corr-tile formation + MFMA MLP --------------
__global__ __launch_bounds__(512, 1) void main_kernel(
    const float* __restrict__ x, const unsigned short* __restrict__ W1T,
    const unsigned short* __restrict__ W2T, const unsigned short* __restrict__ xd,
    const float* __restrict__ W3, float* __restrict__ acc) {
  // LDS: W1 tile [64 f][264 k] + corr tile [32 r][264 k] (reused as h1 f32) +
  //      double-buffered x window + z3 partials  (~53 KB)
  __shared__ __align__(16) unsigned short w1t[64 * 264];
  __shared__ __align__(16) unsigned short cr[BM * 264];
  __shared__ __align__(16) unsigned short xwin[2][3][XW_LEN];
  __shared__ float z3p[64];

  const int t = threadIdx.x;
  const int i0 = blockIdx.x * BM;
  const int w = t >> 6, l = t & 63;
  const int lg = l >> 4, lr = l & 15;

  // formation thread coords (threads 0..255): 8 row-groups x 32 col-groups
  const int cg = t & 31, rg = (t >> 5) & 7;
  const int r0 = rg * 4, jj0 = cg * 8;

  float xw[3][4];
  if (t < 256) {
#pragma unroll
    for (int c = 0; c < 3; ++c)
#pragma unroll
      for (int r = 0; r < 4; ++r)
        xw[c][r] = x[c * NN + i0 + r0 + r];
  }

  // prologue: stage x window for tile 0 into buffer 0
  if (t < 114) {
    int c = t / 38, r = t - c * 38;
    *(uint4*)&xwin[0][c][r * 8] = *(const uint4*)&xd[c * XD_LEN + i0 + r * 8];
  }

  floatx4 acc00 = {0.f, 0.f, 0.f, 0.f}, acc01 = {0.f, 0.f, 0.f, 0.f};
  floatx4 acc10 = {0.f, 0.f, 0.f, 0.f}, acc11 = {0.f, 0.f, 0.f, 0.f};
  const int np = w & 1, quad = w >> 1;   // k-parity-split wave map

  __syncthreads();

  for (int kt = 0; kt < NN / BK; ++kt) {
    const int j0 = kt * BK;
    const int buf = kt & 1;
    if (t < 256) {
      // ---- corr tile formation: 4x8 register subtile, diagonal reuse ----
      float accf[4][8];
#pragma unroll
      for (int r = 0; r < 4; ++r)
#pragma unroll
        for (int j = 0; j < 8; ++j) accf[r][j] = 0.f;
      const int s = r0 + jj0;   // window start (mult of 4 -> aligned b64 reads)
#pragma unroll
      for (int c = 0; c < 3; ++c) {
        const unsigned short* xb = &xwin[buf][c][s];
        ushort4 w0 = *(const ushort4*)(xb);
        ushort4 w1v = *(const ushort4*)(xb + 4);
        ushort4 w2v = *(const ushort4*)(xb + 8);
        float wf[12];
        wf[0] = bf2f(w0.x);  wf[1] = bf2f(w0.y);  wf[2] = bf2f(w0.z);  wf[3] = bf2f(w0.w);
        wf[4] = bf2f(w1v.x); wf[5] = bf2f(w1v.y); wf[6] = bf2f(w1v.z); wf[7] = bf2f(w1v.w);
        wf[8] = bf2f(w2v.x); wf[9] = bf2f(w2v.y); wf[10] = bf2f(w2v.z); wf[11] = bf2f(w2v.w);
#pragma unroll
        for (int r = 0; r < 4; ++r) {
          float wv = xw[c][r];
#pragma unroll
          for (int j = 0; j < 8; ++j) accf[r][j] = fmaf(wv, wf[r + j], accf[r][j]);
        }
      }
#pragma unroll
      for (int r = 0; r < 4; ++r) {
        unsigned q0 = (unsigned)f2bf(accf[r][0]) | ((unsigned)f2bf(accf[r][1]) << 16);
        unsigned q1 = (unsigned)f2bf(accf[r][2]) | ((unsigned)f2bf(accf[r][3]) << 16);
        unsigned q2 = (unsigned)f2bf(accf[r][4]) | ((unsigned)f2bf(accf[r][5]) << 16);
        unsigned q3 = (unsigned)f2bf(accf[r][6]) | ((unsigned)f2bf(accf[r][7]) << 16);
        uint4 q = {q0, q1, q2, q3};
        *(uint4*)&cr[(r0 + r) * 264 + jj0] = q;
      }
    } else {
      // ---- staging half: W1 tile (this kt) + x window (kt+1) ----
      const int ts = t - 256;
      const int f = ts >> 2, qq = ts & 3;
      const int kp0 = qq * 64;
#pragma unroll
      for (int i = 0; i < 8; ++i) {
        *(uint4*)&w1t[f * 264 + kp0 + i * 8] =
            *(const uint4*)&W1T[f * NN + j0 + kp0 + i * 8];
      }
      if (kt + 1 < NN / BK && ts < 114) {
        int c = ts / 38, r = ts - c * 38;
        *(uint4*)&xwin[buf ^ 1][c][r * 8] =
            *(const uint4*)&xd[c * XD_LEN + i0 + j0 + BK + r * 8];
      }
    }
    __syncthreads();
    // ---- MFMA: each wave owns (n-pair np, ks in {quad, quad+4}), both m ----
#pragma unroll
    for (int s2 = 0; s2 < 2; ++s2) {
      const int kb = (quad + s2 * 4) * 32 + lg * 8;
      bfrag8 a0 = __builtin_bit_cast(bfrag8, *(const uint4*)&cr[lr * 264 + kb]);
      bfrag8 a1 = __builtin_bit_cast(bfrag8, *(const uint4*)&cr[(16 + lr) * 264 + kb]);
      bfrag8 b0 = __builtin_bit_cast(bfrag8, *(const uint4*)&w1t[(np * 32 + lr) * 264 + kb]);
      bfrag8 b1 = __builtin_bit_cast(bfrag8, *(const uint4*)&w1t[(np * 32 + 16 + lr) * 264 + kb]);
      acc00 = __builtin_amdgcn_mfma_f32_16x16x32_bf16(a0, b0, acc00, 0, 0, 0);
      acc01 = __builtin_amdgcn_mfma_f32_16x16x32_bf16(a0, b1, acc01, 0, 0, 0);
      acc10 = __builtin_amdgcn_mfma_f32_16x16x32_bf16(a1, b0, acc10, 0, 0, 0);
      acc11 = __builtin_amdgcn_mfma_f32_16x16x32_bf16(a1, b1, acc11, 0, 0, 0);
    }
    __syncthreads();
  }

  // ---- combine k-split partial accumulators into h1 (f32, reuses cr) ----
  float* h1buf = (float*)cr;   // [32][68]
  for (int q = t; q < 32 * 68; q += 512) h1buf[q] = 0.f;
  __syncthreads();
  {
#pragma unroll
    for (int m = 0; m < 2; ++m)
#pragma unroll
      for (int tn = 0; tn < 2; ++tn) {
        floatx4 a = (m == 0) ? (tn == 0 ? acc00 : acc01) : (tn == 0 ? acc10 : acc11);
#pragma unroll
        for (int r = 0; r < 4; ++r) {
          int row = m * 16 + lg * 4 + r;
          int col = np * 32 + tn * 16 + lr;
          atomicAdd(&h1buf[row * 68 + col], a[r]);
        }
      }
  }
  __syncthreads();

  // ---- layer 2 (elu(h1) @ W2) + layer 3 (@ W3) + row reduction ----
  if (t < 256) {
    const int m2 = w & 1, np2 = w >> 1;
    floatx4 acc2_0 = {0.f, 0.f, 0.f, 0.f}, acc2_1 = {0.f, 0.f, 0.f, 0.f};
#pragma unroll
    for (int ks2 = 0; ks2 < 2; ++ks2) {
      const int kb = ks2 * 32 + lg * 8;
      const float* hp = &h1buf[(m2 * 16 + lr) * 68 + kb];
      unsigned qa[4];
#pragma unroll
      for (int e = 0; e < 4; ++e) {
        float v0 = elu(hp[2 * e]), v1 = elu(hp[2 * e + 1]);
        qa[e] = (unsigned)f2bf(v0) | ((unsigned)f2bf(v1) << 16);
      }
      uint4 qv = {qa[0], qa[1], qa[2], qa[3]};
      bfrag8 a2 = __builtin_bit_cast(bfrag8, qv);
#pragma unroll
      for (int tn = 0; tn < 2; ++tn) {
        int col2 = np2 * 32 + tn * 16 + lr;
        bfrag8 b2 = __builtin_bit_cast(bfrag8, *(const uint4*)&W2T[col2 * 64 + kb]);
        if (tn == 0)
          acc2_0 = __builtin_amdgcn_mfma_f32_16x16x32_bf16(a2, b2, acc2_0, 0, 0, 0);
        else
          acc2_1 = __builtin_amdgcn_mfma_f32_16x16x32_bf16(a2, b2, acc2_1, 0, 0, 0);
      }
    }
    float w3a = W3[np2 * 32 + lr];
    float w3b = W3[np2 * 32 + 16 + lr];
    float vsum[4];
#pragma unroll
    for (int r = 0; r < 4; ++r) {
      float v = elu(acc2_0[r]) * w3a + elu(acc2_1[r]) * w3b;
      v += __shfl_xor(v, 1); v += __shfl_xor(v, 2);
      v += __shfl_xor(v, 4); v += __shfl_xor(v, 8);
      vsum[r] = v;
    }
    if (lr == 0) {
#pragma unroll
      for (int r = 0; r < 4; ++r)
        z3p[(m2 * 16 + lg * 4 + r) * 2 + np2] = vsum[r];
    }
  }
  __syncthreads();
  if (t < 32) {
    float sv = z3p[t * 2] + z3p[t * 2 + 1];
    float z3 = elu(sv);
    z3 += __shfl_xor(z3, 1); z3 += __shfl_xor(z3, 2); z3 += __shfl_xor(z3, 4);
    z3 += __shfl_xor(z3, 8); z3 += __shfl_xor(z3, 16);
    if (t == 0) atomicAdd(&acc[0], z3);
  }
}

// ---------------- finalize ------------------------------------------------
__global__ void fin_kernel(const float* __restrict__ acc, const float* __restrict__ regu2,
                           const float* __restrict__ regu, float* __restrict__ out) {
  if (threadIdx.x == 0)
    out[0] = acc[0] * (1.f / (float)NN) - regu2[0] * acc[1] - regu[0] * acc[2];
}

extern "C" void kernel_launch(void* const* d_in, const int* in_sizes, int n_in,
                              void* d_out, int out_size, void* d_ws, size_t ws_size,
                              hipStream_t stream) {
  const float* x     = (const float*)d_in[0];
  const float* W1    = (const float*)d_in[1];
  const float* W2    = (const float*)d_in[2];
  const float* W3    = (const float*)d_in[3];
  const float* regu2 = (const float*)d_in[4];
  const float* regu  = (const float*)d_in[5];
  const float* rlen  = (const float*)d_in[6];

  char* ws = (char*)d_ws;
  float* acc            = (float*)ws;                       // [0]=sum z3, [1]=sum x2, [2]=sum exp
  unsigned short* W1T   = (unsigned short*)(ws + 16);       // 64*8192 bf16 = 1 MB
  unsigned short* W2T   = (unsigned short*)(ws + 1048592);  // 64*64 bf16
  unsigned short* xd    = (unsigned short*)(ws + 1056784);  // 3*16448 bf16 (x duplicated)

  (void)hipMemsetAsync(acc, 0, 16, stream);
  prep_kernel<<<132, 256, 0, stream>>>(x, W1, W2, rlen, W1T, W2T, xd, acc);
  main_kernel<<<256, 512, 0, stream>>>(x, W1T, W2T, xd, W3, acc);
  fin_kernel<<<1, 64, 0, stream>>>(acc, regu2, regu, (float*)d_out);
}

// Round 6
// 120.269 us; speedup vs baseline: 1.2149x; 1.2149x over previous
//
#include <hip/hip_runtime.h>
#include <hip/hip_bf16.h>

#define NN 8192
#define BM 32
#define BK 256
#define NT (NN / BK)      // 32 K-tiles
#define XWF 304           // per-tile f32 window length (288 used, padded)

typedef short bfrag8 __attribute__((ext_vector_type(8)));   // 8 bf16 in 4 VGPRs
typedef float floatx4 __attribute__((ext_vector_type(4)));

static __device__ __forceinline__ unsigned short f2bf(float f) {
  unsigned u = __builtin_bit_cast(unsigned, f);
  u = (u + 0x7FFFu + ((u >> 16) & 1u)) >> 16;   // RNE
  return (unsigned short)u;
}
static __device__ __forceinline__ unsigned cvt_pk_bf16(float a, float b) {
  return (unsigned)f2bf(a) | ((unsigned)f2bf(b) << 16);
}
static __device__ __forceinline__ float elu(float v) {
  return v > 0.f ? v : expm1f(v);
}

// ---------------- prep: W1^T bf16, W2^T bf16, regu sums --------------------
__global__ void prep_kernel(const float* __restrict__ x, const float* __restrict__ W1,
                            const float* __restrict__ W2, const float* __restrict__ rlen,
                            unsigned short* __restrict__ W1T, unsigned short* __restrict__ W2T,
                            float* __restrict__ acc) {
  const int b = blockIdx.x, t = threadIdx.x;
  if (b < 128) {
    // transpose a 64x64 tile of W1 (8192x64) -> W1T (64x8192) bf16
    __shared__ float tile[64][65];
    const int k0 = b * 64;
#pragma unroll
    for (int it = 0; it < 16; ++it) {
      int k = it * 4 + (t >> 6);
      tile[k][t & 63] = W1[(k0 + k) * 64 + (t & 63)];
    }
    __syncthreads();
#pragma unroll
    for (int it = 0; it < 16; ++it) {
      int f = it * 4 + (t >> 6);
      int kk = t & 63;
      W1T[f * NN + k0 + kk] = f2bf(tile[kk][f]);
    }
  } else if (b == 128) {
    for (int idx = t; idx < 64 * 64; idx += 256) {
      int k = idx >> 6, f = idx & 63;
      W2T[f * 64 + k] = f2bf(W2[idx]);
    }
  } else {
    // blocks 129,130: x2 = sum_c x^2; s1 = sum x2, s2 = sum exp(x2/(2 L^2))
    float rl = rlen[0];
    float inv = 1.f / (2.f * rl * rl);
    int base = (b - 129) * 4096;
    float s1 = 0.f, s2 = 0.f;
    for (int ii = 0; ii < 16; ++ii) {
      int i = base + ii * 256 + t;
      float a0 = x[i], a1 = x[NN + i], a2 = x[2 * NN + i];
      float s = a0 * a0 + a1 * a1 + a2 * a2;
      s1 += s; s2 += expf(s * inv);
    }
    for (int d = 32; d > 0; d >>= 1) { s1 += __shfl_down(s1, d); s2 += __shfl_down(s2, d); }
    __shared__ float p1[4], p2[4];
    if ((t & 63) == 0) { p1[t >> 6] = s1; p2[t >> 6] = s2; }
    __syncthreads();
    if (t == 0) {
      atomicAdd(&acc[1], p1[0] + p1[1] + p1[2] + p1[3]);
      atomicAdd(&acc[2], p2[0] + p2[1] + p2[2] + p2[3]);
    }
  }
}

// ---------------- main: fused corr formation + MFMA MLP --------------------
// cr: double-buffered bf16 corr tile, 32 rows x 256 cols, row stride 512 B,
//     rotation-swizzled 16B slots: phys = (slot + 4*row) & 31.
// B operand (W1T rows) prefetched global->VGPR one tile ahead. One barrier/tile.
__global__ __launch_bounds__(512, 1) void main_kernel(
    const float* __restrict__ x, const unsigned short* __restrict__ W1T,
    const unsigned short* __restrict__ W2T, const float* __restrict__ W3,
    float* __restrict__ acc) {
  __shared__ __align__(16) unsigned short cr[2][BM * 256];   // 32 KB
  __shared__ __align__(16) float xwinf[2][3][XWF];           // 7.3 KB
  __shared__ float z3p[64];

  const int t = threadIdx.x;
  const int i0 = blockIdx.x * BM;
  const int wv = t >> 6;            // wave id 0..7 = formation row group
  const int l = t & 63;
  const int lg = l >> 4, lr = l & 15;

  // formation coords: wave wv owns rows [wv*4, wv*4+4); lane cg owns 4 cols
  const int cg = l;                 // 0..63, cols [cg*4, cg*4+4)
  const int sb = wv * 4 + cg * 4;   // window base (mult of 4 -> 16B aligned)

  // MFMA wave mapping (identical operands to verified Round-2 kernel)
  const int np = wv & 1, quad = wv >> 1;
  const unsigned short* bp0 = W1T + (np * 32 + lr) * NN + quad * 32 + lg * 8;
  const unsigned short* bp1 = bp0 + 16 * NN;

  // x row values for formation
  float xr[3][4];
#pragma unroll
  for (int c = 0; c < 3; ++c)
#pragma unroll
    for (int r = 0; r < 4; ++r)
      xr[c][r] = x[c * NN + i0 + wv * 4 + r];

  // prologue: stage window for tile 0; load B fragments for tile 0
  if (t < 216) {
    int c = t / 72, rr = t - c * 72;
    *(float4*)&xwinf[0][c][rr * 4] =
        *(const float4*)&x[c * NN + ((i0 + rr * 4) & (NN - 1))];
  }
  uint4 bA0 = *(const uint4*)(bp0);         // s2=0, row np*32+lr
  uint4 bA1 = *(const uint4*)(bp1);         // s2=0, row np*32+16+lr
  uint4 bB0 = *(const uint4*)(bp0 + 128);   // s2=1
  uint4 bB1 = *(const uint4*)(bp1 + 128);

  floatx4 acc00 = {0.f, 0.f, 0.f, 0.f}, acc01 = {0.f, 0.f, 0.f, 0.f};
  floatx4 acc10 = {0.f, 0.f, 0.f, 0.f}, acc11 = {0.f, 0.f, 0.f, 0.f};

  __syncthreads();

  for (int kt = 0; kt < NT; ++kt) {
    const int j0 = kt * BK;
    const int buf = kt & 1;
    const int jn = j0 + BK;
    const bool more = (kt + 1 < NT);

    // ---- issue next-tile prefetches (window f32 -> reg, B frags -> reg) ----
    float4 sv;
    int c_st = 0, rr_st = 0;
    const bool do_stage = more && (t < 216);
    if (do_stage) {
      c_st = t / 72; rr_st = t - c_st * 72;
      sv = *(const float4*)&x[c_st * NN + ((i0 + jn + rr_st * 4) & (NN - 1))];
    }
    uint4 nA0, nA1, nB0, nB1;
    if (more) {
      nA0 = *(const uint4*)(bp0 + jn);
      nA1 = *(const uint4*)(bp1 + jn);
      nB0 = *(const uint4*)(bp0 + jn + 128);
      nB1 = *(const uint4*)(bp1 + jn + 128);
    }

    // ---- corr tile formation: 4 rows x 4 cols per thread ----
    float acf[4][4];
#pragma unroll
    for (int r = 0; r < 4; ++r)
#pragma unroll
      for (int j = 0; j < 4; ++j) acf[r][j] = 0.f;
#pragma unroll
    for (int c = 0; c < 3; ++c) {
      const float* wp = &xwinf[buf][c][sb];
      float4 v0 = *(const float4*)(wp);
      float4 v1 = *(const float4*)(wp + 4);
      float wf[7] = {v0.x, v0.y, v0.z, v0.w, v1.x, v1.y, v1.z};
#pragma unroll
      for (int r = 0; r < 4; ++r) {
        float xv = xr[c][r];
#pragma unroll
        for (int j = 0; j < 4; ++j) acf[r][j] = fmaf(xv, wf[r + j], acf[r][j]);
      }
    }
    // swizzled bf16 write: row = wv*4+r, logical slot = cg>>1, half = cg&1
#pragma unroll
    for (int r = 0; r < 4; ++r) {
      const int row = wv * 4 + r;
      const int sw = ((cg >> 1) + 4 * row) & 31;
      unsigned u0 = cvt_pk_bf16(acf[r][0], acf[r][1]);
      unsigned u1 = cvt_pk_bf16(acf[r][2], acf[r][3]);
      uint2 q = {u0, u1};
      *(uint2*)((char*)&cr[buf][0] + row * 512 + sw * 16 + (cg & 1) * 8) = q;
    }
    // ---- write staged window for next tile ----
    if (do_stage) *(float4*)&xwinf[buf ^ 1][c_st][rr_st * 4] = sv;

    __syncthreads();

    // ---- MFMA: A from swizzled cr, B from prefetched VGPRs ----
#pragma unroll
    for (int s2 = 0; s2 < 2; ++s2) {
      const int slot = (quad + s2 * 4) * 4 + lg;
      const int swz = (slot + 4 * lr) & 31;   // rows lr and 16+lr share (4*row)&31
      bfrag8 a0 = __builtin_bit_cast(bfrag8,
          *(const uint4*)((const char*)&cr[buf][0] + lr * 512 + swz * 16));
      bfrag8 a1 = __builtin_bit_cast(bfrag8,
          *(const uint4*)((const char*)&cr[buf][0] + (16 + lr) * 512 + swz * 16));
      bfrag8 b0 = __builtin_bit_cast(bfrag8, s2 == 0 ? bA0 : bB0);
      bfrag8 b1 = __builtin_bit_cast(bfrag8, s2 == 0 ? bA1 : bB1);
      acc00 = __builtin_amdgcn_mfma_f32_16x16x32_bf16(a0, b0, acc00, 0, 0, 0);
      acc01 = __builtin_amdgcn_mfma_f32_16x16x32_bf16(a0, b1, acc01, 0, 0, 0);
      acc10 = __builtin_amdgcn_mfma_f32_16x16x32_bf16(a1, b0, acc10, 0, 0, 0);
      acc11 = __builtin_amdgcn_mfma_f32_16x16x32_bf16(a1, b1, acc11, 0, 0, 0);
    }
    bA0 = nA0; bA1 = nA1; bB0 = nB0; bB1 = nB1;
  }

  // ---- combine k-split partial accumulators into h1 (f32, reuses cr[0]) ----
  float* h1buf = (float*)&cr[0][0];   // [32][68] = 8704 B (within buffer 0)
  for (int q = t; q < 32 * 68; q += 512) h1buf[q] = 0.f;
  __syncthreads();
  {
#pragma unroll
    for (int m = 0; m < 2; ++m)
#pragma unroll
      for (int tn = 0; tn < 2; ++tn) {
        floatx4 a = (m == 0) ? (tn == 0 ? acc00 : acc01) : (tn == 0 ? acc10 : acc11);
#pragma unroll
        for (int r = 0; r < 4; ++r) {
          int row = m * 16 + lg * 4 + r;
          int col = np * 32 + tn * 16 + lr;
          atomicAdd(&h1buf[row * 68 + col], a[r]);
        }
      }
  }
  __syncthreads();

  // ---- layer 2 (elu(h1) @ W2) + layer 3 (@ W3) + row reduction ----
  if (t < 256) {
    const int w4 = t >> 6;
    const int m2 = w4 & 1, np2 = w4 >> 1;
    floatx4 acc2_0 = {0.f, 0.f, 0.f, 0.f}, acc2_1 = {0.f, 0.f, 0.f, 0.f};
#pragma unroll
    for (int ks2 = 0; ks2 < 2; ++ks2) {
      const int kb = ks2 * 32 + lg * 8;
      const float* hp = &h1buf[(m2 * 16 + lr) * 68 + kb];
      unsigned qa[4];
#pragma unroll
      for (int e = 0; e < 4; ++e) {
        float v0 = elu(hp[2 * e]), v1 = elu(hp[2 * e + 1]);
        qa[e] = cvt_pk_bf16(v0, v1);
      }
      uint4 qv = {qa[0], qa[1], qa[2], qa[3]};
      bfrag8 a2 = __builtin_bit_cast(bfrag8, qv);
#pragma unroll
      for (int tn = 0; tn < 2; ++tn) {
        int col2 = np2 * 32 + tn * 16 + lr;
        bfrag8 b2 = __builtin_bit_cast(bfrag8, *(const uint4*)&W2T[col2 * 64 + kb]);
        if (tn == 0)
          acc2_0 = __builtin_amdgcn_mfma_f32_16x16x32_bf16(a2, b2, acc2_0, 0, 0, 0);
        else
          acc2_1 = __builtin_amdgcn_mfma_f32_16x16x32_bf16(a2, b2, acc2_1, 0, 0, 0);
      }
    }
    float w3a = W3[np2 * 32 + lr];
    float w3b = W3[np2 * 32 + 16 + lr];
    float vsum[4];
#pragma unroll
    for (int r = 0; r < 4; ++r) {
      float v = elu(acc2_0[r]) * w3a + elu(acc2_1[r]) * w3b;
      v += __shfl_xor(v, 1); v += __shfl_xor(v, 2);
      v += __shfl_xor(v, 4); v += __shfl_xor(v, 8);
      vsum[r] = v;
    }
    if (lr == 0) {
#pragma unroll
      for (int r = 0; r < 4; ++r)
        z3p[(m2 * 16 + lg * 4 + r) * 2 + np2] = vsum[r];
    }
  }
  __syncthreads();
  if (t < 32) {
    float sv2 = z3p[t * 2] + z3p[t * 2 + 1];
    float z3 = elu(sv2);
    z3 += __shfl_xor(z3, 1); z3 += __shfl_xor(z3, 2); z3 += __shfl_xor(z3, 4);
    z3 += __shfl_xor(z3, 8); z3 += __shfl_xor(z3, 16);
    if (t == 0) atomicAdd(&acc[0], z3);
  }
}

// ---------------- finalize ------------------------------------------------
__global__ void fin_kernel(const float* __restrict__ acc, const float* __restrict__ regu2,
                           const float* __restrict__ regu, float* __restrict__ out) {
  if (threadIdx.x == 0)
    out[0] = acc[0] * (1.f / (float)NN) - regu2[0] * acc[1] - regu[0] * acc[2];
}

extern "C" void kernel_launch(void* const* d_in, const int* in_sizes, int n_in,
                              void* d_out, int out_size, void* d_ws, size_t ws_size,
                              hipStream_t stream) {
  const float* x     = (const float*)d_in[0];
  const float* W1    = (const float*)d_in[1];
  const float* W2    = (const float*)d_in[2];
  const float* W3    = (const float*)d_in[3];
  const float* regu2 = (const float*)d_in[4];
  const float* regu  = (const float*)d_in[5];
  const float* rlen  = (const float*)d_in[6];

  char* ws = (char*)d_ws;
  float* acc            = (float*)ws;                       // [0]=sum z3, [1]=sum x2, [2]=sum exp
  unsigned short* W1T   = (unsigned short*)(ws + 16);       // 64*8192 bf16 = 1 MB
  unsigned short* W2T   = (unsigned short*)(ws + 1048592);  // 64*64 bf16

  (void)hipMemsetAsync(acc, 0, 16, stream);
  prep_kernel<<<131, 256, 0, stream>>>(x, W1, W2, rlen, W1T, W2T, acc);
  main_kernel<<<256, 512, 0, stream>>>(x, W1T, W2T, W3, acc);
  fin_kernel<<<1, 64, 0, stream>>>(acc, regu2, regu, (float*)d_out);
}